// Round 14
// baseline (378.101 us; speedup 1.0000x reference)
//
#include <hip/hip_runtime.h>
#include <hip/hip_fp16.h>
#include <math.h>

#define NEG_SLOPE 0.2f
#define GB 192           // gemm sub-grid of the fused front kernel
#define SB 320           // binning sub-grid (R27: reverted to 320 — SB=512 cost +8us in store runs)
#define CHMAX 11264      // 11*1024 register-cached edges per binning block
#define CAP 5120         // slab capacity per 128-node bucket; mean 4224, sigma 65
#define CAPH 2560        // per-half clamp (front/back disjoint by construction)

typedef _Float16 half2v __attribute__((ext_vector_type(2)));
typedef _Float16 half4v __attribute__((ext_vector_type(4)));

// exact algebraic mish: x*tanh(log1p(e^x)) == x*((1+e^x)^2-1)/((1+e^x)^2+1)
__device__ __forceinline__ float mishf(float x) {
    if (x > 15.f) return x;            // tanh(softplus)==1 to 1e-13
    float ex = __expf(x);
    float y = 1.f + ex;
    float y2 = y * y;
    return x * (y2 - 1.f) / (y2 + 1.f);
}

__device__ __forceinline__ float lw(float e) {  // exp(leakyrelu(e))
    return __expf(fmaxf(e, NEG_SLOPE * e));
}

__device__ __forceinline__ float hdot2a(half2v a, half2v b, float c) {
#if __has_builtin(__builtin_amdgcn_fdot2)
    return __builtin_amdgcn_fdot2(a, b, c, false);
#else
    return (float)a.x * (float)b.x + (float)a.y * (float)b.y + c;
#endif
}

// ---- Fused front (R25 form, byte-identical): blocks [0,GB) run the layer-1
// node GEMM; blocks [GB,GB+SB) run the edge binning with per-block LDS
// counting sort so the global write-out is j-coalesced.
__global__ __launch_bounds__(1024) void front_kernel(
        const float* __restrict__ x, const float* __restrict__ W1,
        const float* __restrict__ a_dst,
        const float* __restrict__ W2, const float* __restrict__ as2,
        const float* __restrict__ ad2,
        _Float16* __restrict__ hpre1h, float* __restrict__ addst,
        float* __restrict__ vs, float* __restrict__ vd,
        const int* __restrict__ src, const int* __restrict__ dst,
        int E, int Etot, int CH, int NB, int N, int NT,
        int* __restrict__ cursor, int* __restrict__ pairs) {
    __shared__ __attribute__((aligned(16))) char smem[63824];
    int tid = threadIdx.x;
    if (blockIdx.x < GB) {
        // ---------------- GEMM part: hpre1h = fp16(x @ W1), addst ----------
        float* Wlt = (float*)smem;          // [16][132] transposed W1
        float* xs  = Wlt + 16 * 132;        // [64][132] x tile
        if (blockIdx.x == 0 && tid < 16) {
            float ps = 0.f, pd = 0.f;
            #pragma unroll
            for (int c = 0; c < 32; c++) {
                float w = W2[tid * 32 + c];
                ps += w * as2[c];
                pd += w * ad2[c];
            }
            vs[tid] = ps; vd[tid] = pd;
        }
        for (int i = tid; i < 2048; i += 1024) Wlt[(i & 15) * 132 + (i >> 4)] = W1[i];
        int nl = tid >> 4, ch = tid & 15;
        for (int t = blockIdx.x; t < NT; t += GB) {
            int nodebase = t * 64;
            int nvalid = min(64, N - nodebase);
            __syncthreads();               // previous tile's reads done
            const float4* x4 = (const float4*)(x + (size_t)nodebase * 128);
            #pragma unroll
            for (int u = 0; u < 2; u++) {
                int i = tid + (u << 10);
                int tnl = i >> 5;          // node-local (each node = 32 float4)
                if (tnl < nvalid) {
                    float4 v = x4[i];
                    int k = (i & 31) * 4;
                    float* dp = &xs[tnl * 132 + k];
                    dp[0] = v.x; dp[1] = v.y; dp[2] = v.z; dp[3] = v.w;
                }
            }
            __syncthreads();
            if (nl < nvalid) {
                const float4* xr4 = (const float4*)&xs[nl * 132];
                const float4* wr4 = (const float4*)&Wlt[ch * 132];
                float acc = 0.f;
                #pragma unroll
                for (int k4 = 0; k4 < 32; k4++) {
                    float4 xv = xr4[k4];
                    float4 wv = wr4[k4];
                    acc += xv.x * wv.x + xv.y * wv.y + xv.z * wv.z + xv.w * wv.w;
                }
                int node = nodebase + nl;
                hpre1h[node * 16 + ch] = (_Float16)acc;
                float pd = acc * a_dst[ch];
                pd += __shfl_xor(pd, 1); pd += __shfl_xor(pd, 2);
                if ((ch & 3) == 0) addst[node * 4 + (ch >> 2)] = pd;
            }
        }
    } else {
        // ---------------- binning part: LDS counting sort + coalesced out --
        int nb2 = 2 * NB;
        int* A    = (int*)smem;             // [nb2] counts -> ranks
        int* Boff = A + nb2;                // [nb2] inclusive scan -> excl. offsets
        int* C    = Boff + nb2;             // [nb2] reserved global start per f
        int* buf  = C + nb2;                // [CHMAX] payload, bucket-ordered
        int blk = blockIdx.x - GB;
        for (int b = tid; b < nb2; b += 1024) A[b] = 0;
        __syncthreads();
        int ibeg = blk * CH, iend = min((blk + 1) * CH, Etot);
        int cdv[11], cs[11];
        #pragma unroll
        for (int u = 0; u < 11; u++) {      // tid + u*1024 < CHMAX always
            int i = ibeg + tid + (u << 10);
            int d = -1, s = 0;
            if (i < iend) {
                if (i < E) { d = dst[i]; s = src[i]; } else { d = i - E; s = d; }
                atomicAdd(&A[d >> 6], 1);
            }
            cdv[u] = d; cs[u] = s;
        }
        // tail beyond CHMAX (normally empty): slow direct path, still correct
        for (int i = ibeg + CHMAX + tid; i < iend; i += 1024) {
            int d, s;
            if (i < E) { d = dst[i]; s = src[i]; } else { d = i - E; s = d; }
            int f = d >> 6;
            int pos = atomicAdd(&cursor[f], 1);
            pos = pos < CAPH ? pos : CAPH - 1;
            size_t addr = (size_t)(f >> 1) * CAP + ((f & 1) ? (CAP - 1 - pos) : pos);
            pairs[addr] = s | ((d & 63) << 17);
        }
        __syncthreads();
        for (int b = tid; b < nb2; b += 1024) Boff[b] = A[b];
        __syncthreads();
        for (int o = 1; o < nb2; o <<= 1) {  // Hillis-Steele inclusive scan
            int i1 = tid, i2 = tid + 1024;
            int v1 = 0, v2 = 0;
            if (i1 < nb2 && i1 >= o) v1 = Boff[i1 - o];
            if (i2 < nb2 && i2 >= o) v2 = Boff[i2 - o];
            __syncthreads();
            if (i1 < nb2) Boff[i1] += v1;
            if (i2 < nb2) Boff[i2] += v2;
            __syncthreads();
        }
        for (int b = tid; b < nb2; b += 1024) {
            int cnt = A[b];
            Boff[b] -= cnt;                 // exclusive start
            C[b] = cnt ? atomicAdd(&cursor[b], cnt) : 0;
        }
        __syncthreads();
        for (int b = tid; b < nb2; b += 1024) A[b] = 0;   // ranks
        __syncthreads();
        #pragma unroll
        for (int u = 0; u < 11; u++) {
            int d = cdv[u];
            if (d < 0) continue;
            int f = d >> 6;
            int r = atomicAdd(&A[f], 1);
            buf[Boff[f] + r] = cs[u] | ((d & 63) << 17);
        }
        __syncthreads();
        int total = iend - ibeg;
        if (total > CHMAX) total = CHMAX;
        if (total < 0) total = 0;
        for (int j = tid; j < total; j += 1024) {
            int lo = 0, hi = nb2 - 1;       // last f with Boff[f] <= j
            while (lo < hi) {
                int mid = (lo + hi + 1) >> 1;
                if (Boff[mid] <= j) lo = mid; else hi = mid - 1;
            }
            int f = lo;
            int pos = C[f] + (j - Boff[f]);
            pos = pos < CAPH ? pos : CAPH - 1;
            size_t addr = (size_t)(f >> 1) * CAP + ((f & 1) ? (CAP - 1 - pos) : pos);
            pairs[addr] = buf[j];
        }
    }
}

// ---- Per-half CSR build + layer-1 softmax-aggregate (R25 form: head-per-
// lane 4ch, adaptive-compute 4-volley).
__global__ __launch_bounds__(256) void csragg1_kernel(
        const int* __restrict__ pairs, const int* __restrict__ btotal,
        int NB, int N,
        int* __restrict__ ssorted, int* __restrict__ rs, int* __restrict__ re,
        const float* __restrict__ a_src1, const float* __restrict__ addst,
        const _Float16* __restrict__ hpre1h, const float* __restrict__ b1,
        const float* __restrict__ vs, const float* __restrict__ vd,
        _Float16* __restrict__ hpost1h,
        float* __restrict__ as2n, float* __restrict__ ad2n) {
    __shared__ int deg[64];
    __shared__ int s[64];
    __shared__ int cur[64];
    __shared__ __attribute__((aligned(16))) int lds_sorted[CAPH];
    int tid = threadIdx.x, bh = blockIdx.x;
    int B = bh >> 1, half = bh & 1;
    int nb0 = (B << 7) + (half << 6);
    int cnt_nodes = min(64, N - nb0);      // may be <= 0 for the tail half
    int c = min(btotal[bh], CAPH);         // this half's edge count
    int rbase = B * CAP + (half ? CAP - c : 0);
    if (tid < 64) deg[tid] = 0;
    __syncthreads();
    for (int j = tid; j < c; j += 256)
        atomicAdd(&deg[(pairs[rbase + j] >> 17) & 63], 1);
    __syncthreads();
    if (tid < 64) s[tid] = deg[tid];
    __syncthreads();
    for (int o = 1; o < 64; o <<= 1) {
        int v = 0;
        if (tid < 64 && tid >= o) v = s[tid - o];
        __syncthreads();
        if (tid < 64) s[tid] += v;
        __syncthreads();
    }
    if (tid < 64) {
        int ex = s[tid] - deg[tid];        // half-local exclusive offset
        cur[tid] = ex;
        if (tid < cnt_nodes) {
            rs[nb0 + tid] = bh * CAPH + ex;   // global ssorted offsets for agg2
            re[nb0 + tid] = bh * CAPH + ex + deg[tid];
        }
    }
    __syncthreads();
    for (int j = tid; j < c; j += 256) {   // 2nd region read: L2-hot
        int p = pairs[rbase + j];
        int pos = atomicAdd(&cur[(p >> 17) & 63], 1);
        lds_sorted[pos < CAPH ? pos : CAPH - 1] = p & 0x1FFFF;
    }
    __syncthreads();

    // Coalesced stream-out for agg2 (fire-and-forget; phase B reads only LDS).
    {
        int t4 = c >> 2;
        const int4* ls4 = (const int4*)lds_sorted;
        int4* gs4 = (int4*)(ssorted + (size_t)bh * CAPH);
        for (int j = tid; j < t4; j += 256) gs4[j] = ls4[j];
        for (int j = (t4 << 2) + tid; j < c; j += 256)
            ssorted[(size_t)bh * CAPH + j] = lds_sorted[j];
    }

    // Phase B: wave w handles nodes ln = w*16 + r. head-per-lane,
    // adaptive-compute 4-volley.
    int wave = tid >> 6;
    int lane = tid & 63;
    int head = lane & 3, er = lane >> 2;
    int c0 = head * 4;
    half2v w01, w23;
    w01.x = (_Float16)a_src1[c0];     w01.y = (_Float16)a_src1[c0 + 1];
    w23.x = (_Float16)a_src1[c0 + 2]; w23.y = (_Float16)a_src1[c0 + 3];
    for (int r = 0; r < 16; r++) {
        int ln = (wave << 4) + r;
        if (ln >= cnt_nodes) break;
        int node = nb0 + ln;
        int end = cur[ln];                 // half-local end
        int start = end - deg[ln];
        float adh = addst[node * 4 + head];
        float den = 0.f, a0 = 0.f, a1 = 0.f, a2 = 0.f, a3 = 0.f;
        int last = end - 1;   // deg >= 1 always (self-loop)
        for (int jb = start; jb < end; jb += 64) {
            int m = end - jb;              // wave-uniform remaining count
            int j0 = jb + er, j1 = j0 + 16, j2 = j0 + 32, j3 = j0 + 48;
            int k0 = min(j0, last), k1 = min(j1, last);
            int k2 = min(j2, last), k3 = min(j3, last);
            int s0 = lds_sorted[k0];
            int s1 = lds_sorted[k1];
            int s2 = lds_sorted[k2];
            int s3 = lds_sorted[k3];
            half4v h0 = *(const half4v*)(hpre1h + (size_t)s0 * 16 + c0);
            half4v h1 = *(const half4v*)(hpre1h + (size_t)s1 * 16 + c0);
            half4v h2 = *(const half4v*)(hpre1h + (size_t)s2 * 16 + c0);
            half4v h3 = *(const half4v*)(hpre1h + (size_t)s3 * 16 + c0);
            {   // slot group 0: always
                float p0 = hdot2a(__builtin_shufflevector(h0, h0, 0, 1), w01,
                           hdot2a(__builtin_shufflevector(h0, h0, 2, 3), w23, 0.f));
                float wt0 = (j0 <= last) ? lw(p0 + adh) : 0.f;
                den += wt0;
                a0 += (float)h0.x * wt0; a1 += (float)h0.y * wt0;
                a2 += (float)h0.z * wt0; a3 += (float)h0.w * wt0;
            }
            if (m > 16) {
                float p1 = hdot2a(__builtin_shufflevector(h1, h1, 0, 1), w01,
                           hdot2a(__builtin_shufflevector(h1, h1, 2, 3), w23, 0.f));
                float wt1 = (j1 <= last) ? lw(p1 + adh) : 0.f;
                den += wt1;
                a0 += (float)h1.x * wt1; a1 += (float)h1.y * wt1;
                a2 += (float)h1.z * wt1; a3 += (float)h1.w * wt1;
            }
            if (m > 32) {
                float p2 = hdot2a(__builtin_shufflevector(h2, h2, 0, 1), w01,
                           hdot2a(__builtin_shufflevector(h2, h2, 2, 3), w23, 0.f));
                float wt2 = (j2 <= last) ? lw(p2 + adh) : 0.f;
                den += wt2;
                a0 += (float)h2.x * wt2; a1 += (float)h2.y * wt2;
                a2 += (float)h2.z * wt2; a3 += (float)h2.w * wt2;
            }
            if (m > 48) {
                float p3 = hdot2a(__builtin_shufflevector(h3, h3, 0, 1), w01,
                           hdot2a(__builtin_shufflevector(h3, h3, 2, 3), w23, 0.f));
                float wt3 = (j3 <= last) ? lw(p3 + adh) : 0.f;
                den += wt3;
                a0 += (float)h3.x * wt3; a1 += (float)h3.y * wt3;
                a2 += (float)h3.z * wt3; a3 += (float)h3.w * wt3;
            }
        }
        a0 += __shfl_xor(a0, 4);  a1 += __shfl_xor(a1, 4);  a2 += __shfl_xor(a2, 4);  a3 += __shfl_xor(a3, 4);  den += __shfl_xor(den, 4);
        a0 += __shfl_xor(a0, 8);  a1 += __shfl_xor(a1, 8);  a2 += __shfl_xor(a2, 8);  a3 += __shfl_xor(a3, 8);  den += __shfl_xor(den, 8);
        a0 += __shfl_xor(a0, 16); a1 += __shfl_xor(a1, 16); a2 += __shfl_xor(a2, 16); a3 += __shfl_xor(a3, 16); den += __shfl_xor(den, 16);
        a0 += __shfl_xor(a0, 32); a1 += __shfl_xor(a1, 32); a2 += __shfl_xor(a2, 32); a3 += __shfl_xor(a3, 32); den += __shfl_xor(den, 32);
        if (er == 0) {
            float inv = 1.f / (den + 1e-16f);
            float o0 = mishf(a0 * inv + b1[c0]);
            float o1 = mishf(a1 * inv + b1[c0 + 1]);
            float o2 = mishf(a2 * inv + b1[c0 + 2]);
            float o3 = mishf(a3 * inv + b1[c0 + 3]);
            half4v oh;
            oh.x = (_Float16)o0; oh.y = (_Float16)o1;
            oh.z = (_Float16)o2; oh.w = (_Float16)o3;
            *(half4v*)(hpost1h + (size_t)node * 16 + c0) = oh;
            float ps = o0 * vs[c0] + o1 * vs[c0 + 1] + o2 * vs[c0 + 2] + o3 * vs[c0 + 3];
            float pd = o0 * vd[c0] + o1 * vd[c0 + 1] + o2 * vd[c0 + 2] + o3 * vd[c0 + 3];
            ps += __shfl_xor(ps, 1); pd += __shfl_xor(pd, 1);
            ps += __shfl_xor(ps, 2); pd += __shfl_xor(pd, 2);
            if (head == 0) { as2n[node] = ps; ad2n[node] = pd; }
        }
    }
}

// ---- Layer-2 softmax-aggregate (R25 form: one node per wave, quarter-per-
// lane 4ch, adaptive-compute volley).
__global__ __launch_bounds__(256) void agg2_kernel(
        const int* __restrict__ rs, const int* __restrict__ re,
        const int* __restrict__ ssorted,
        const float* __restrict__ as2n, const float* __restrict__ ad2n,
        const _Float16* __restrict__ hpost1h,
        float* __restrict__ agg16, float* __restrict__ denv, int N) {
    int wave = threadIdx.x >> 6;
    int lane = threadIdx.x & 63;
    int node = blockIdx.x * 4 + wave;
    if (node >= N) return;
    int start = rs[node], end = re[node];
    int q = lane & 3, er = lane >> 2;
    int c0 = q * 4;
    float adh = ad2n[node];
    const _Float16* hb = hpost1h + c0;
    float den = 0.f, a0 = 0.f, a1 = 0.f, a2 = 0.f, a3 = 0.f;
    int last = end - 1;
    for (int jb = start; jb < end; jb += 64) {
        int m = end - jb;                  // wave-uniform remaining count
        int j0 = jb + er, j1 = j0 + 16, j2 = j0 + 32, j3 = j0 + 48;
        int k0 = min(j0, last), k1 = min(j1, last);
        int k2 = min(j2, last), k3 = min(j3, last);
        int s0 = __builtin_nontemporal_load(ssorted + k0);
        int s1 = __builtin_nontemporal_load(ssorted + k1);
        int s2 = __builtin_nontemporal_load(ssorted + k2);
        int s3 = __builtin_nontemporal_load(ssorted + k3);
        float v0 = as2n[s0];
        float v1 = as2n[s1];
        float v2 = as2n[s2];
        float v3 = as2n[s3];
        half4v h0 = *(const half4v*)(hb + (size_t)s0 * 16);
        half4v h1 = *(const half4v*)(hb + (size_t)s1 * 16);
        half4v h2 = *(const half4v*)(hb + (size_t)s2 * 16);
        half4v h3 = *(const half4v*)(hb + (size_t)s3 * 16);
        {   // slot group 0: always
            float wt0 = (j0 <= last) ? lw(v0 + adh) : 0.f;
            den += wt0;
            a0 += (float)h0.x * wt0; a1 += (float)h0.y * wt0;
            a2 += (float)h0.z * wt0; a3 += (float)h0.w * wt0;
        }
        if (m > 16) {
            float wt1 = (j1 <= last) ? lw(v1 + adh) : 0.f;
            den += wt1;
            a0 += (float)h1.x * wt1; a1 += (float)h1.y * wt1;
            a2 += (float)h1.z * wt1; a3 += (float)h1.w * wt1;
        }
        if (m > 32) {
            float wt2 = (j2 <= last) ? lw(v2 + adh) : 0.f;
            den += wt2;
            a0 += (float)h2.x * wt2; a1 += (float)h2.y * wt2;
            a2 += (float)h2.z * wt2; a3 += (float)h2.w * wt2;
        }
        if (m > 48) {
            float wt3 = (j3 <= last) ? lw(v3 + adh) : 0.f;
            den += wt3;
            a0 += (float)h3.x * wt3; a1 += (float)h3.y * wt3;
            a2 += (float)h3.z * wt3; a3 += (float)h3.w * wt3;
        }
    }
    a0 += __shfl_xor(a0, 4);  a1 += __shfl_xor(a1, 4);  a2 += __shfl_xor(a2, 4);  a3 += __shfl_xor(a3, 4);  den += __shfl_xor(den, 4);
    a0 += __shfl_xor(a0, 8);  a1 += __shfl_xor(a1, 8);  a2 += __shfl_xor(a2, 8);  a3 += __shfl_xor(a3, 8);  den += __shfl_xor(den, 8);
    a0 += __shfl_xor(a0, 16); a1 += __shfl_xor(a1, 16); a2 += __shfl_xor(a2, 16); a3 += __shfl_xor(a3, 16); den += __shfl_xor(den, 16);
    a0 += __shfl_xor(a0, 32); a1 += __shfl_xor(a1, 32); a2 += __shfl_xor(a2, 32); a3 += __shfl_xor(a3, 32); den += __shfl_xor(den, 32);
    if (er == 0) {
        float4 o; o.x = a0; o.y = a1; o.z = a2; o.w = a3;
        *(float4*)(agg16 + (size_t)node * 16 + c0) = o;
        if (q == 0) denv[node] = den;
    }
}

// ---- Fused layer-2 GEMM epilogue + mean pool (R27: back to the proven 128
// nodes/block — R13's 64-node split doubled pool atomics into an 8KB region
// and cost 57us). NEW: the LAST block (device-scope done-counter) performs
// the finalize in-kernel, removing the fin dispatch. pool/cnt are read via
// atomicAdd(p, 0) — device-scope coherent, immune to XCD-L2 staleness (G16).
__global__ void post2pool_kernel(const float* __restrict__ agg16, const float* __restrict__ denv,
                                 const float* __restrict__ W2, const float* __restrict__ b2,
                                 const int* __restrict__ batch,
                                 float* __restrict__ pool, float* __restrict__ cnt,
                                 int* __restrict__ done, float* __restrict__ out,
                                 int NG, int N) {
    __shared__ float Wl[16 * 32];
    __shared__ int is_last;
    int tid = threadIdx.x;
    for (int i = tid; i < 512; i += 256) Wl[i] = W2[i];
    __syncthreads();
    int r = tid >> 5, ch = tid & 31;
    float bc = b2[ch];
    int base = blockIdx.x * 128;
    int cur = -1;
    float sum = 0.f, c = 0.f;
    for (int it = 0; it < 16; it++) {
        int n = base + it * 8 + r;
        if (n >= N) break;
        int g = batch[n];
        if (g != cur) {
            if (cur >= 0) {
                atomicAdd(&pool[cur * 32 + ch], sum);
                if (ch == 0) atomicAdd(&cnt[cur], c);
            }
            cur = g; sum = 0.f; c = 0.f;
        }
        const float* ar = agg16 + (size_t)n * 16;
        float acc = 0.f;
        #pragma unroll
        for (int k = 0; k < 16; k++) acc += ar[k] * Wl[k * 32 + ch];
        float val = mishf(acc / (denv[n] + 1e-16f) + bc);
        sum += val;
        c += 1.f;
    }
    if (cur >= 0) {
        atomicAdd(&pool[cur * 32 + ch], sum);
        if (ch == 0) atomicAdd(&cnt[cur], c);
    }
    // ---- last-block finalize (replaces fin_kernel dispatch) ----
    __threadfence();
    __syncthreads();
    if (tid == 0) {
        int old = atomicAdd(done, 1);
        is_last = (old == (int)gridDim.x - 1);
    }
    __syncthreads();
    if (is_last) {
        __threadfence();
        for (int i = tid; i < NG * 32; i += 256) {
            float pv = atomicAdd(&pool[i], 0.f);        // coherent read
            float cv = atomicAdd(&cnt[i >> 5], 0.f);    // coherent read
            out[i] = pv / fmaxf(cv, 1.0f);
        }
    }
}

extern "C" void kernel_launch(void* const* d_in, const int* in_sizes, int n_in,
                              void* d_out, int out_size, void* d_ws, size_t ws_size,
                              hipStream_t stream) {
    const float* x   = (const float*)d_in[0];
    const int* eidx  = (const int*)d_in[1];
    const int* batch = (const int*)d_in[2];
    const float* W1  = (const float*)d_in[3];
    const float* b1  = (const float*)d_in[4];
    const float* as1 = (const float*)d_in[5];
    const float* ad1 = (const float*)d_in[6];
    const float* W2  = (const float*)d_in[7];
    const float* b2  = (const float*)d_in[8];
    const float* as2 = (const float*)d_in[9];
    const float* ad2 = (const float*)d_in[10];
    float* out = (float*)d_out;

    int N = in_sizes[0] / 128;
    int E = in_sizes[1] / 2;
    int Etot = E + N;
    int NG = out_size / 32;
    const int* esrc = eidx;
    const int* edst = eidx + E;

    int NB = (N + 127) >> 7;                 // 128-node slabs (binning grain)
    int NBH = NB * 2;                        // 64-node halves (aggregate grain)
    int NT = (N + 63) >> 6;                  // 64-node gemm tiles
    int CH = (Etot + SB - 1) / SB;           // edges per binning block

    char* p = (char*)d_ws;
    auto alloc = [&](size_t nbytes) {
        p = (char*)(((uintptr_t)p + 15) & ~(uintptr_t)15);
        void* r = (void*)p; p += nbytes; return r;
    };
    int* pairs        = (int*)alloc((size_t)NB * CAP * 4);
    int* ssorted      = (int*)alloc((size_t)NBH * CAPH * 4);
    int* rs           = (int*)alloc((size_t)N * 4);
    int* re           = (int*)alloc((size_t)N * 4);
    _Float16* hpre1h  = (_Float16*)alloc((size_t)N * 16 * 2);
    _Float16* hpost1h = (_Float16*)alloc((size_t)N * 16 * 2);
    float* addst1  = (float*)alloc((size_t)N * 4 * 4);
    float* as2n    = (float*)alloc((size_t)N * 4);
    float* ad2n    = (float*)alloc((size_t)N * 4);
    float* agg16   = (float*)alloc((size_t)N * 16 * 4);
    float* denv    = (float*)alloc((size_t)N * 4);
    float* vs      = (float*)alloc(16 * 4);
    float* vd      = (float*)alloc(16 * 4);
    // ---- zero-init region: cursor + pool + cnt + done, contiguous, ONE memset
    char* zbase    = (char*)(((uintptr_t)p + 15) & ~(uintptr_t)15);
    int* cursor    = (int*)alloc((size_t)NBH * 4);
    float* pool    = (float*)alloc((size_t)NG * 32 * 4);
    float* cnt     = (float*)alloc((size_t)NG * 4);
    int* done      = (int*)alloc(4);
    size_t zbytes  = (size_t)(p - zbase);

    hipMemsetAsync(zbase, 0, zbytes, stream);

    front_kernel<<<GB + SB, 1024, 0, stream>>>(x, W1, ad1, W2, as2, ad2,
                                               hpre1h, addst1, vs, vd,
                                               esrc, edst, E, Etot, CH, NB, N, NT,
                                               cursor, pairs);
    csragg1_kernel<<<NBH, 256, 0, stream>>>(pairs, cursor, NB, N,
                                            ssorted, rs, re, as1, addst1, hpre1h,
                                            b1, vs, vd, hpost1h, as2n, ad2n);
    agg2_kernel<<<(N + 3) / 4, 256, 0, stream>>>(rs, re, ssorted, as2n, ad2n, hpost1h,
                                                 agg16, denv, N);
    post2pool_kernel<<<(N + 127) / 128, 256, 0, stream>>>(agg16, denv, W2, b2, batch,
                                                          pool, cnt, done, out, NG, N);
}

// Round 15
// 320.809 us; speedup vs baseline: 1.1786x; 1.1786x over previous
//
#include <hip/hip_runtime.h>
#include <hip/hip_fp16.h>
#include <math.h>

#define NEG_SLOPE 0.2f
#define GB 192           // gemm sub-grid of the fused front kernel
#define SB 320           // binning sub-grid
#define CHMAX 11264      // 11*1024 register-cached edges per binning block
#define CAP 5120         // slab capacity per 128-node bucket; mean 4224, sigma 65
#define CAPH 2560        // per-half clamp (front/back disjoint by construction)

typedef _Float16 half2v __attribute__((ext_vector_type(2)));
typedef _Float16 half4v __attribute__((ext_vector_type(4)));

// exact algebraic mish: x*tanh(log1p(e^x)) == x*((1+e^x)^2-1)/((1+e^x)^2+1)
__device__ __forceinline__ float mishf(float x) {
    if (x > 15.f) return x;            // tanh(softplus)==1 to 1e-13
    float ex = __expf(x);
    float y = 1.f + ex;
    float y2 = y * y;
    return x * (y2 - 1.f) / (y2 + 1.f);
}

__device__ __forceinline__ float lw(float e) {  // exp(leakyrelu(e))
    return __expf(fmaxf(e, NEG_SLOPE * e));
}

__device__ __forceinline__ float hdot2a(half2v a, half2v b, float c) {
#if __has_builtin(__builtin_amdgcn_fdot2)
    return __builtin_amdgcn_fdot2(a, b, c, false);
#else
    return (float)a.x * (float)b.x + (float)a.y * (float)b.y + c;
#endif
}

// ---- Fused front (R25 form, byte-identical): blocks [0,GB) run the layer-1
// node GEMM; blocks [GB,GB+SB) run the edge binning with per-block LDS
// counting sort so the global write-out is j-coalesced.
__global__ __launch_bounds__(1024) void front_kernel(
        const float* __restrict__ x, const float* __restrict__ W1,
        const float* __restrict__ a_dst,
        const float* __restrict__ W2, const float* __restrict__ as2,
        const float* __restrict__ ad2,
        _Float16* __restrict__ hpre1h, float* __restrict__ addst,
        float* __restrict__ vs, float* __restrict__ vd,
        const int* __restrict__ src, const int* __restrict__ dst,
        int E, int Etot, int CH, int NB, int N, int NT,
        int* __restrict__ cursor, int* __restrict__ pairs) {
    __shared__ __attribute__((aligned(16))) char smem[63824];
    int tid = threadIdx.x;
    if (blockIdx.x < GB) {
        // ---------------- GEMM part: hpre1h = fp16(x @ W1), addst ----------
        float* Wlt = (float*)smem;          // [16][132] transposed W1
        float* xs  = Wlt + 16 * 132;        // [64][132] x tile
        if (blockIdx.x == 0 && tid < 16) {
            float ps = 0.f, pd = 0.f;
            #pragma unroll
            for (int c = 0; c < 32; c++) {
                float w = W2[tid * 32 + c];
                ps += w * as2[c];
                pd += w * ad2[c];
            }
            vs[tid] = ps; vd[tid] = pd;
        }
        for (int i = tid; i < 2048; i += 1024) Wlt[(i & 15) * 132 + (i >> 4)] = W1[i];
        int nl = tid >> 4, ch = tid & 15;
        for (int t = blockIdx.x; t < NT; t += GB) {
            int nodebase = t * 64;
            int nvalid = min(64, N - nodebase);
            __syncthreads();               // previous tile's reads done
            const float4* x4 = (const float4*)(x + (size_t)nodebase * 128);
            #pragma unroll
            for (int u = 0; u < 2; u++) {
                int i = tid + (u << 10);
                int tnl = i >> 5;          // node-local (each node = 32 float4)
                if (tnl < nvalid) {
                    float4 v = x4[i];
                    int k = (i & 31) * 4;
                    float* dp = &xs[tnl * 132 + k];
                    dp[0] = v.x; dp[1] = v.y; dp[2] = v.z; dp[3] = v.w;
                }
            }
            __syncthreads();
            if (nl < nvalid) {
                const float4* xr4 = (const float4*)&xs[nl * 132];
                const float4* wr4 = (const float4*)&Wlt[ch * 132];
                float acc = 0.f;
                #pragma unroll
                for (int k4 = 0; k4 < 32; k4++) {
                    float4 xv = xr4[k4];
                    float4 wv = wr4[k4];
                    acc += xv.x * wv.x + xv.y * wv.y + xv.z * wv.z + xv.w * wv.w;
                }
                int node = nodebase + nl;
                hpre1h[node * 16 + ch] = (_Float16)acc;
                float pd = acc * a_dst[ch];
                pd += __shfl_xor(pd, 1); pd += __shfl_xor(pd, 2);
                if ((ch & 3) == 0) addst[node * 4 + (ch >> 2)] = pd;
            }
        }
    } else {
        // ---------------- binning part: LDS counting sort + coalesced out --
        int nb2 = 2 * NB;
        int* A    = (int*)smem;             // [nb2] counts -> ranks
        int* Boff = A + nb2;                // [nb2] inclusive scan -> excl. offsets
        int* C    = Boff + nb2;             // [nb2] reserved global start per f
        int* buf  = C + nb2;                // [CHMAX] payload, bucket-ordered
        int blk = blockIdx.x - GB;
        for (int b = tid; b < nb2; b += 1024) A[b] = 0;
        __syncthreads();
        int ibeg = blk * CH, iend = min((blk + 1) * CH, Etot);
        int cdv[11], cs[11];
        #pragma unroll
        for (int u = 0; u < 11; u++) {      // tid + u*1024 < CHMAX always
            int i = ibeg + tid + (u << 10);
            int d = -1, s = 0;
            if (i < iend) {
                if (i < E) { d = dst[i]; s = src[i]; } else { d = i - E; s = d; }
                atomicAdd(&A[d >> 6], 1);
            }
            cdv[u] = d; cs[u] = s;
        }
        // tail beyond CHMAX (normally empty): slow direct path, still correct
        for (int i = ibeg + CHMAX + tid; i < iend; i += 1024) {
            int d, s;
            if (i < E) { d = dst[i]; s = src[i]; } else { d = i - E; s = d; }
            int f = d >> 6;
            int pos = atomicAdd(&cursor[f], 1);
            pos = pos < CAPH ? pos : CAPH - 1;
            size_t addr = (size_t)(f >> 1) * CAP + ((f & 1) ? (CAP - 1 - pos) : pos);
            pairs[addr] = s | ((d & 63) << 17);
        }
        __syncthreads();
        for (int b = tid; b < nb2; b += 1024) Boff[b] = A[b];
        __syncthreads();
        for (int o = 1; o < nb2; o <<= 1) {  // Hillis-Steele inclusive scan
            int i1 = tid, i2 = tid + 1024;
            int v1 = 0, v2 = 0;
            if (i1 < nb2 && i1 >= o) v1 = Boff[i1 - o];
            if (i2 < nb2 && i2 >= o) v2 = Boff[i2 - o];
            __syncthreads();
            if (i1 < nb2) Boff[i1] += v1;
            if (i2 < nb2) Boff[i2] += v2;
            __syncthreads();
        }
        for (int b = tid; b < nb2; b += 1024) {
            int cnt = A[b];
            Boff[b] -= cnt;                 // exclusive start
            C[b] = cnt ? atomicAdd(&cursor[b], cnt) : 0;
        }
        __syncthreads();
        for (int b = tid; b < nb2; b += 1024) A[b] = 0;   // ranks
        __syncthreads();
        #pragma unroll
        for (int u = 0; u < 11; u++) {
            int d = cdv[u];
            if (d < 0) continue;
            int f = d >> 6;
            int r = atomicAdd(&A[f], 1);
            buf[Boff[f] + r] = cs[u] | ((d & 63) << 17);
        }
        __syncthreads();
        int total = iend - ibeg;
        if (total > CHMAX) total = CHMAX;
        if (total < 0) total = 0;
        for (int j = tid; j < total; j += 1024) {
            int lo = 0, hi = nb2 - 1;       // last f with Boff[f] <= j
            while (lo < hi) {
                int mid = (lo + hi + 1) >> 1;
                if (Boff[mid] <= j) lo = mid; else hi = mid - 1;
            }
            int f = lo;
            int pos = C[f] + (j - Boff[f]);
            pos = pos < CAPH ? pos : CAPH - 1;
            size_t addr = (size_t)(f >> 1) * CAP + ((f & 1) ? (CAP - 1 - pos) : pos);
            pairs[addr] = buf[j];
        }
    }
}

// ---- Per-half CSR build + layer-1 softmax-aggregate (R25 form: head-per-
// lane 4ch, adaptive-compute 4-volley).
__global__ __launch_bounds__(256) void csragg1_kernel(
        const int* __restrict__ pairs, const int* __restrict__ btotal,
        int NB, int N,
        int* __restrict__ ssorted, int* __restrict__ rs, int* __restrict__ re,
        const float* __restrict__ a_src1, const float* __restrict__ addst,
        const _Float16* __restrict__ hpre1h, const float* __restrict__ b1,
        const float* __restrict__ vs, const float* __restrict__ vd,
        _Float16* __restrict__ hpost1h,
        float* __restrict__ as2n, float* __restrict__ ad2n) {
    __shared__ int deg[64];
    __shared__ int s[64];
    __shared__ int cur[64];
    __shared__ __attribute__((aligned(16))) int lds_sorted[CAPH];
    int tid = threadIdx.x, bh = blockIdx.x;
    int B = bh >> 1, half = bh & 1;
    int nb0 = (B << 7) + (half << 6);
    int cnt_nodes = min(64, N - nb0);      // may be <= 0 for the tail half
    int c = min(btotal[bh], CAPH);         // this half's edge count
    int rbase = B * CAP + (half ? CAP - c : 0);
    if (tid < 64) deg[tid] = 0;
    __syncthreads();
    for (int j = tid; j < c; j += 256)
        atomicAdd(&deg[(pairs[rbase + j] >> 17) & 63], 1);
    __syncthreads();
    if (tid < 64) s[tid] = deg[tid];
    __syncthreads();
    for (int o = 1; o < 64; o <<= 1) {
        int v = 0;
        if (tid < 64 && tid >= o) v = s[tid - o];
        __syncthreads();
        if (tid < 64) s[tid] += v;
        __syncthreads();
    }
    if (tid < 64) {
        int ex = s[tid] - deg[tid];        // half-local exclusive offset
        cur[tid] = ex;
        if (tid < cnt_nodes) {
            rs[nb0 + tid] = bh * CAPH + ex;   // global ssorted offsets for agg2
            re[nb0 + tid] = bh * CAPH + ex + deg[tid];
        }
    }
    __syncthreads();
    for (int j = tid; j < c; j += 256) {   // 2nd region read: L2-hot
        int p = pairs[rbase + j];
        int pos = atomicAdd(&cur[(p >> 17) & 63], 1);
        lds_sorted[pos < CAPH ? pos : CAPH - 1] = p & 0x1FFFF;
    }
    __syncthreads();

    // Coalesced stream-out for agg2 (fire-and-forget; phase B reads only LDS).
    {
        int t4 = c >> 2;
        const int4* ls4 = (const int4*)lds_sorted;
        int4* gs4 = (int4*)(ssorted + (size_t)bh * CAPH);
        for (int j = tid; j < t4; j += 256) gs4[j] = ls4[j];
        for (int j = (t4 << 2) + tid; j < c; j += 256)
            ssorted[(size_t)bh * CAPH + j] = lds_sorted[j];
    }

    // Phase B: wave w handles nodes ln = w*16 + r. head-per-lane,
    // adaptive-compute 4-volley.
    int wave = tid >> 6;
    int lane = tid & 63;
    int head = lane & 3, er = lane >> 2;
    int c0 = head * 4;
    half2v w01, w23;
    w01.x = (_Float16)a_src1[c0];     w01.y = (_Float16)a_src1[c0 + 1];
    w23.x = (_Float16)a_src1[c0 + 2]; w23.y = (_Float16)a_src1[c0 + 3];
    for (int r = 0; r < 16; r++) {
        int ln = (wave << 4) + r;
        if (ln >= cnt_nodes) break;
        int node = nb0 + ln;
        int end = cur[ln];                 // half-local end
        int start = end - deg[ln];
        float adh = addst[node * 4 + head];
        float den = 0.f, a0 = 0.f, a1 = 0.f, a2 = 0.f, a3 = 0.f;
        int last = end - 1;   // deg >= 1 always (self-loop)
        for (int jb = start; jb < end; jb += 64) {
            int m = end - jb;              // wave-uniform remaining count
            int j0 = jb + er, j1 = j0 + 16, j2 = j0 + 32, j3 = j0 + 48;
            int k0 = min(j0, last), k1 = min(j1, last);
            int k2 = min(j2, last), k3 = min(j3, last);
            int s0 = lds_sorted[k0];
            int s1 = lds_sorted[k1];
            int s2 = lds_sorted[k2];
            int s3 = lds_sorted[k3];
            half4v h0 = *(const half4v*)(hpre1h + (size_t)s0 * 16 + c0);
            half4v h1 = *(const half4v*)(hpre1h + (size_t)s1 * 16 + c0);
            half4v h2 = *(const half4v*)(hpre1h + (size_t)s2 * 16 + c0);
            half4v h3 = *(const half4v*)(hpre1h + (size_t)s3 * 16 + c0);
            {   // slot group 0: always
                float p0 = hdot2a(__builtin_shufflevector(h0, h0, 0, 1), w01,
                           hdot2a(__builtin_shufflevector(h0, h0, 2, 3), w23, 0.f));
                float wt0 = (j0 <= last) ? lw(p0 + adh) : 0.f;
                den += wt0;
                a0 += (float)h0.x * wt0; a1 += (float)h0.y * wt0;
                a2 += (float)h0.z * wt0; a3 += (float)h0.w * wt0;
            }
            if (m > 16) {
                float p1 = hdot2a(__builtin_shufflevector(h1, h1, 0, 1), w01,
                           hdot2a(__builtin_shufflevector(h1, h1, 2, 3), w23, 0.f));
                float wt1 = (j1 <= last) ? lw(p1 + adh) : 0.f;
                den += wt1;
                a0 += (float)h1.x * wt1; a1 += (float)h1.y * wt1;
                a2 += (float)h1.z * wt1; a3 += (float)h1.w * wt1;
            }
            if (m > 32) {
                float p2 = hdot2a(__builtin_shufflevector(h2, h2, 0, 1), w01,
                           hdot2a(__builtin_shufflevector(h2, h2, 2, 3), w23, 0.f));
                float wt2 = (j2 <= last) ? lw(p2 + adh) : 0.f;
                den += wt2;
                a0 += (float)h2.x * wt2; a1 += (float)h2.y * wt2;
                a2 += (float)h2.z * wt2; a3 += (float)h2.w * wt2;
            }
            if (m > 48) {
                float p3 = hdot2a(__builtin_shufflevector(h3, h3, 0, 1), w01,
                           hdot2a(__builtin_shufflevector(h3, h3, 2, 3), w23, 0.f));
                float wt3 = (j3 <= last) ? lw(p3 + adh) : 0.f;
                den += wt3;
                a0 += (float)h3.x * wt3; a1 += (float)h3.y * wt3;
                a2 += (float)h3.z * wt3; a3 += (float)h3.w * wt3;
            }
        }
        a0 += __shfl_xor(a0, 4);  a1 += __shfl_xor(a1, 4);  a2 += __shfl_xor(a2, 4);  a3 += __shfl_xor(a3, 4);  den += __shfl_xor(den, 4);
        a0 += __shfl_xor(a0, 8);  a1 += __shfl_xor(a1, 8);  a2 += __shfl_xor(a2, 8);  a3 += __shfl_xor(a3, 8);  den += __shfl_xor(den, 8);
        a0 += __shfl_xor(a0, 16); a1 += __shfl_xor(a1, 16); a2 += __shfl_xor(a2, 16); a3 += __shfl_xor(a3, 16); den += __shfl_xor(den, 16);
        a0 += __shfl_xor(a0, 32); a1 += __shfl_xor(a1, 32); a2 += __shfl_xor(a2, 32); a3 += __shfl_xor(a3, 32); den += __shfl_xor(den, 32);
        if (er == 0) {
            float inv = 1.f / (den + 1e-16f);
            float o0 = mishf(a0 * inv + b1[c0]);
            float o1 = mishf(a1 * inv + b1[c0 + 1]);
            float o2 = mishf(a2 * inv + b1[c0 + 2]);
            float o3 = mishf(a3 * inv + b1[c0 + 3]);
            half4v oh;
            oh.x = (_Float16)o0; oh.y = (_Float16)o1;
            oh.z = (_Float16)o2; oh.w = (_Float16)o3;
            *(half4v*)(hpost1h + (size_t)node * 16 + c0) = oh;
            float ps = o0 * vs[c0] + o1 * vs[c0 + 1] + o2 * vs[c0 + 2] + o3 * vs[c0 + 3];
            float pd = o0 * vd[c0] + o1 * vd[c0 + 1] + o2 * vd[c0 + 2] + o3 * vd[c0 + 3];
            ps += __shfl_xor(ps, 1); pd += __shfl_xor(pd, 1);
            ps += __shfl_xor(ps, 2); pd += __shfl_xor(pd, 2);
            if (head == 0) { as2n[node] = ps; ad2n[node] = pd; }
        }
    }
}

// ---- Layer-2 softmax-aggregate (R25 form: one node per wave, quarter-per-
// lane 4ch, adaptive-compute volley).
__global__ __launch_bounds__(256) void agg2_kernel(
        const int* __restrict__ rs, const int* __restrict__ re,
        const int* __restrict__ ssorted,
        const float* __restrict__ as2n, const float* __restrict__ ad2n,
        const _Float16* __restrict__ hpost1h,
        float* __restrict__ agg16, float* __restrict__ denv, int N) {
    int wave = threadIdx.x >> 6;
    int lane = threadIdx.x & 63;
    int node = blockIdx.x * 4 + wave;
    if (node >= N) return;
    int start = rs[node], end = re[node];
    int q = lane & 3, er = lane >> 2;
    int c0 = q * 4;
    float adh = ad2n[node];
    const _Float16* hb = hpost1h + c0;
    float den = 0.f, a0 = 0.f, a1 = 0.f, a2 = 0.f, a3 = 0.f;
    int last = end - 1;
    for (int jb = start; jb < end; jb += 64) {
        int m = end - jb;                  // wave-uniform remaining count
        int j0 = jb + er, j1 = j0 + 16, j2 = j0 + 32, j3 = j0 + 48;
        int k0 = min(j0, last), k1 = min(j1, last);
        int k2 = min(j2, last), k3 = min(j3, last);
        int s0 = __builtin_nontemporal_load(ssorted + k0);
        int s1 = __builtin_nontemporal_load(ssorted + k1);
        int s2 = __builtin_nontemporal_load(ssorted + k2);
        int s3 = __builtin_nontemporal_load(ssorted + k3);
        float v0 = as2n[s0];
        float v1 = as2n[s1];
        float v2 = as2n[s2];
        float v3 = as2n[s3];
        half4v h0 = *(const half4v*)(hb + (size_t)s0 * 16);
        half4v h1 = *(const half4v*)(hb + (size_t)s1 * 16);
        half4v h2 = *(const half4v*)(hb + (size_t)s2 * 16);
        half4v h3 = *(const half4v*)(hb + (size_t)s3 * 16);
        {   // slot group 0: always
            float wt0 = (j0 <= last) ? lw(v0 + adh) : 0.f;
            den += wt0;
            a0 += (float)h0.x * wt0; a1 += (float)h0.y * wt0;
            a2 += (float)h0.z * wt0; a3 += (float)h0.w * wt0;
        }
        if (m > 16) {
            float wt1 = (j1 <= last) ? lw(v1 + adh) : 0.f;
            den += wt1;
            a0 += (float)h1.x * wt1; a1 += (float)h1.y * wt1;
            a2 += (float)h1.z * wt1; a3 += (float)h1.w * wt1;
        }
        if (m > 32) {
            float wt2 = (j2 <= last) ? lw(v2 + adh) : 0.f;
            den += wt2;
            a0 += (float)h2.x * wt2; a1 += (float)h2.y * wt2;
            a2 += (float)h2.z * wt2; a3 += (float)h2.w * wt2;
        }
        if (m > 48) {
            float wt3 = (j3 <= last) ? lw(v3 + adh) : 0.f;
            den += wt3;
            a0 += (float)h3.x * wt3; a1 += (float)h3.y * wt3;
            a2 += (float)h3.z * wt3; a3 += (float)h3.w * wt3;
        }
    }
    a0 += __shfl_xor(a0, 4);  a1 += __shfl_xor(a1, 4);  a2 += __shfl_xor(a2, 4);  a3 += __shfl_xor(a3, 4);  den += __shfl_xor(den, 4);
    a0 += __shfl_xor(a0, 8);  a1 += __shfl_xor(a1, 8);  a2 += __shfl_xor(a2, 8);  a3 += __shfl_xor(a3, 8);  den += __shfl_xor(den, 8);
    a0 += __shfl_xor(a0, 16); a1 += __shfl_xor(a1, 16); a2 += __shfl_xor(a2, 16); a3 += __shfl_xor(a3, 16); den += __shfl_xor(den, 16);
    a0 += __shfl_xor(a0, 32); a1 += __shfl_xor(a1, 32); a2 += __shfl_xor(a2, 32); a3 += __shfl_xor(a3, 32); den += __shfl_xor(den, 32);
    if (er == 0) {
        float4 o; o.x = a0; o.y = a1; o.z = a2; o.w = a3;
        *(float4*)(agg16 + (size_t)node * 16 + c0) = o;
        if (q == 0) denv[node] = den;
    }
}

// ---- Fused layer-2 GEMM epilogue + mean pool (exact R25 form: 128 nodes/
// block, no fence/done counter — R14's last-block finalize fence cost +90us).
__global__ void post2pool_kernel(const float* __restrict__ agg16, const float* __restrict__ denv,
                                 const float* __restrict__ W2, const float* __restrict__ b2,
                                 const int* __restrict__ batch,
                                 float* __restrict__ pool, float* __restrict__ cnt, int N) {
    __shared__ float Wl[16 * 32];
    int tid = threadIdx.x;
    for (int i = tid; i < 512; i += 256) Wl[i] = W2[i];
    __syncthreads();
    int r = tid >> 5, ch = tid & 31;
    float bc = b2[ch];
    int base = blockIdx.x * 128;
    int cur = -1;
    float sum = 0.f, c = 0.f;
    for (int it = 0; it < 16; it++) {
        int n = base + it * 8 + r;
        if (n >= N) break;
        int g = batch[n];
        if (g != cur) {
            if (cur >= 0) {
                atomicAdd(&pool[cur * 32 + ch], sum);
                if (ch == 0) atomicAdd(&cnt[cur], c);
            }
            cur = g; sum = 0.f; c = 0.f;
        }
        const float* ar = agg16 + (size_t)n * 16;
        float acc = 0.f;
        #pragma unroll
        for (int k = 0; k < 16; k++) acc += ar[k] * Wl[k * 32 + ch];
        float val = mishf(acc / (denv[n] + 1e-16f) + bc);
        sum += val;
        c += 1.f;
    }
    if (cur >= 0) {
        atomicAdd(&pool[cur * 32 + ch], sum);
        if (ch == 0) atomicAdd(&cnt[cur], c);
    }
}

__global__ void fin_kernel(const float* __restrict__ pool, const float* __restrict__ cnt,
                           float* __restrict__ out, int NG) {
    int i = blockIdx.x * blockDim.x + threadIdx.x;
    if (i >= NG * 32) return;
    out[i] = pool[i] / fmaxf(cnt[i >> 5], 1.0f);
}

extern "C" void kernel_launch(void* const* d_in, const int* in_sizes, int n_in,
                              void* d_out, int out_size, void* d_ws, size_t ws_size,
                              hipStream_t stream) {
    const float* x   = (const float*)d_in[0];
    const int* eidx  = (const int*)d_in[1];
    const int* batch = (const int*)d_in[2];
    const float* W1  = (const float*)d_in[3];
    const float* b1  = (const float*)d_in[4];
    const float* as1 = (const float*)d_in[5];
    const float* ad1 = (const float*)d_in[6];
    const float* W2  = (const float*)d_in[7];
    const float* b2  = (const float*)d_in[8];
    const float* as2 = (const float*)d_in[9];
    const float* ad2 = (const float*)d_in[10];
    float* out = (float*)d_out;

    int N = in_sizes[0] / 128;
    int E = in_sizes[1] / 2;
    int Etot = E + N;
    int NG = out_size / 32;
    const int* esrc = eidx;
    const int* edst = eidx + E;

    int NB = (N + 127) >> 7;                 // 128-node slabs (binning grain)
    int NBH = NB * 2;                        // 64-node halves (aggregate grain)
    int NT = (N + 63) >> 6;                  // 64-node gemm tiles
    int CH = (Etot + SB - 1) / SB;           // edges per binning block

    char* p = (char*)d_ws;
    auto alloc = [&](size_t nbytes) {
        p = (char*)(((uintptr_t)p + 15) & ~(uintptr_t)15);
        void* r = (void*)p; p += nbytes; return r;
    };
    int* pairs        = (int*)alloc((size_t)NB * CAP * 4);
    int* ssorted      = (int*)alloc((size_t)NBH * CAPH * 4);
    int* rs           = (int*)alloc((size_t)N * 4);
    int* re           = (int*)alloc((size_t)N * 4);
    _Float16* hpre1h  = (_Float16*)alloc((size_t)N * 16 * 2);
    _Float16* hpost1h = (_Float16*)alloc((size_t)N * 16 * 2);
    float* addst1  = (float*)alloc((size_t)N * 4 * 4);
    float* as2n    = (float*)alloc((size_t)N * 4);
    float* ad2n    = (float*)alloc((size_t)N * 4);
    float* agg16   = (float*)alloc((size_t)N * 16 * 4);
    float* denv    = (float*)alloc((size_t)N * 4);
    float* vs      = (float*)alloc(16 * 4);
    float* vd      = (float*)alloc(16 * 4);
    // ---- zero-init region: cursor + pool + cnt contiguous -> ONE memset
    // (R14 arithmetic: each removed dispatch boundary ~ 10-14us)
    char* zbase    = (char*)(((uintptr_t)p + 15) & ~(uintptr_t)15);
    int* cursor    = (int*)alloc((size_t)NBH * 4);
    float* pool    = (float*)alloc((size_t)NG * 32 * 4);
    float* cnt     = (float*)alloc((size_t)NG * 4);
    size_t zbytes  = (size_t)(p - zbase);

    hipMemsetAsync(zbase, 0, zbytes, stream);

    front_kernel<<<GB + SB, 1024, 0, stream>>>(x, W1, ad1, W2, as2, ad2,
                                               hpre1h, addst1, vs, vd,
                                               esrc, edst, E, Etot, CH, NB, N, NT,
                                               cursor, pairs);
    csragg1_kernel<<<NBH, 256, 0, stream>>>(pairs, cursor, NB, N,
                                            ssorted, rs, re, as1, addst1, hpre1h,
                                            b1, vs, vd, hpost1h, as2n, ad2n);
    agg2_kernel<<<(N + 3) / 4, 256, 0, stream>>>(rs, re, ssorted, as2n, ad2n, hpost1h,
                                                 agg16, denv, N);
    post2pool_kernel<<<(N + 127) / 128, 256, 0, stream>>>(agg16, denv, W2, b2, batch,
                                                          pool, cnt, N);
    fin_kernel<<<(NG * 32 + 255) / 256, 256, 0, stream>>>(pool, cnt, out, NG);
}

// Round 16
// 318.737 us; speedup vs baseline: 1.1862x; 1.0065x over previous
//
#include <hip/hip_runtime.h>
#include <hip/hip_fp16.h>
#include <math.h>

#define NEG_SLOPE 0.2f
#define GB 128           // gemm sub-grid (R28: 192->128, longer GEMM blocks to balance)
#define SB 384           // binning sub-grid (R28: 320->384; runs 11 ints ~ 44B, near-full lines)
#define CHMAX 9216       // 9*1024 register-cached edges per binning block
#define CAP 5120         // slab capacity per 128-node bucket; mean 4224, sigma 65
#define CAPH 2560        // per-half clamp (front/back disjoint by construction)

typedef _Float16 half2v __attribute__((ext_vector_type(2)));
typedef _Float16 half4v __attribute__((ext_vector_type(4)));

// exact algebraic mish: x*tanh(log1p(e^x)) == x*((1+e^x)^2-1)/((1+e^x)^2+1)
__device__ __forceinline__ float mishf(float x) {
    if (x > 15.f) return x;            // tanh(softplus)==1 to 1e-13
    float ex = __expf(x);
    float y = 1.f + ex;
    float y2 = y * y;
    return x * (y2 - 1.f) / (y2 + 1.f);
}

__device__ __forceinline__ float lw(float e) {  // exp(leakyrelu(e))
    return __expf(fmaxf(e, NEG_SLOPE * e));
}

__device__ __forceinline__ float hdot2a(half2v a, half2v b, float c) {
#if __has_builtin(__builtin_amdgcn_fdot2)
    return __builtin_amdgcn_fdot2(a, b, c, false);
#else
    return (float)a.x * (float)b.x + (float)a.y * (float)b.y + c;
#endif
}

// ---- Fused front. R28: GB/SB rebalanced 192/320 -> 128/384. R15 counters
// (occ 30%, VALU 27%, HBM 12% for 5 rounds) showed the GEMM sub-grid drains
// early, leaving 320 binning blocks over 512 slots with a long retire tail.
// 128 GEMM blocks x 12.2 tiles run ~1.5x longer; 384 binning blocks x 8.6K
// edges run ~17% shorter -> both sub-grids finish together. Binning runs
// shrink 13->11 ints (44B, near-full lines; NOT R13's 4.1-int 512-grain amp).
__global__ __launch_bounds__(1024) void front_kernel(
        const float* __restrict__ x, const float* __restrict__ W1,
        const float* __restrict__ a_dst,
        const float* __restrict__ W2, const float* __restrict__ as2,
        const float* __restrict__ ad2,
        _Float16* __restrict__ hpre1h, float* __restrict__ addst,
        float* __restrict__ vs, float* __restrict__ vd,
        const int* __restrict__ src, const int* __restrict__ dst,
        int E, int Etot, int CH, int NB, int N, int NT,
        int* __restrict__ cursor, int* __restrict__ pairs) {
    __shared__ __attribute__((aligned(16))) char smem[55632];
    int tid = threadIdx.x;
    if (blockIdx.x < GB) {
        // ---------------- GEMM part: hpre1h = fp16(x @ W1), addst ----------
        float* Wlt = (float*)smem;          // [16][132] transposed W1
        float* xs  = Wlt + 16 * 132;        // [64][132] x tile
        if (blockIdx.x == 0 && tid < 16) {
            float ps = 0.f, pd = 0.f;
            #pragma unroll
            for (int c = 0; c < 32; c++) {
                float w = W2[tid * 32 + c];
                ps += w * as2[c];
                pd += w * ad2[c];
            }
            vs[tid] = ps; vd[tid] = pd;
        }
        for (int i = tid; i < 2048; i += 1024) Wlt[(i & 15) * 132 + (i >> 4)] = W1[i];
        int nl = tid >> 4, ch = tid & 15;
        for (int t = blockIdx.x; t < NT; t += GB) {
            int nodebase = t * 64;
            int nvalid = min(64, N - nodebase);
            __syncthreads();               // previous tile's reads done
            const float4* x4 = (const float4*)(x + (size_t)nodebase * 128);
            #pragma unroll
            for (int u = 0; u < 2; u++) {
                int i = tid + (u << 10);
                int tnl = i >> 5;          // node-local (each node = 32 float4)
                if (tnl < nvalid) {
                    float4 v = x4[i];
                    int k = (i & 31) * 4;
                    float* dp = &xs[tnl * 132 + k];
                    dp[0] = v.x; dp[1] = v.y; dp[2] = v.z; dp[3] = v.w;
                }
            }
            __syncthreads();
            if (nl < nvalid) {
                const float4* xr4 = (const float4*)&xs[nl * 132];
                const float4* wr4 = (const float4*)&Wlt[ch * 132];
                float acc = 0.f;
                #pragma unroll
                for (int k4 = 0; k4 < 32; k4++) {
                    float4 xv = xr4[k4];
                    float4 wv = wr4[k4];
                    acc += xv.x * wv.x + xv.y * wv.y + xv.z * wv.z + xv.w * wv.w;
                }
                int node = nodebase + nl;
                hpre1h[node * 16 + ch] = (_Float16)acc;
                float pd = acc * a_dst[ch];
                pd += __shfl_xor(pd, 1); pd += __shfl_xor(pd, 2);
                if ((ch & 3) == 0) addst[node * 4 + (ch >> 2)] = pd;
            }
        }
    } else {
        // ---------------- binning part: LDS counting sort + coalesced out --
        int nb2 = 2 * NB;
        int* A    = (int*)smem;             // [nb2] counts -> ranks
        int* Boff = A + nb2;                // [nb2] inclusive scan -> excl. offsets
        int* C    = Boff + nb2;             // [nb2] reserved global start per f
        int* buf  = C + nb2;                // [CHMAX] payload, bucket-ordered
        int blk = blockIdx.x - GB;
        for (int b = tid; b < nb2; b += 1024) A[b] = 0;
        __syncthreads();
        int ibeg = blk * CH, iend = min((blk + 1) * CH, Etot);
        int cdv[9], cs[9];
        #pragma unroll
        for (int u = 0; u < 9; u++) {       // tid + u*1024 < CHMAX always
            int i = ibeg + tid + (u << 10);
            int d = -1, s = 0;
            if (i < iend) {
                if (i < E) { d = dst[i]; s = src[i]; } else { d = i - E; s = d; }
                atomicAdd(&A[d >> 6], 1);
            }
            cdv[u] = d; cs[u] = s;
        }
        // tail beyond CHMAX (normally empty): slow direct path, still correct
        for (int i = ibeg + CHMAX + tid; i < iend; i += 1024) {
            int d, s;
            if (i < E) { d = dst[i]; s = src[i]; } else { d = i - E; s = d; }
            int f = d >> 6;
            int pos = atomicAdd(&cursor[f], 1);
            pos = pos < CAPH ? pos : CAPH - 1;
            size_t addr = (size_t)(f >> 1) * CAP + ((f & 1) ? (CAP - 1 - pos) : pos);
            pairs[addr] = s | ((d & 63) << 17);
        }
        __syncthreads();
        for (int b = tid; b < nb2; b += 1024) Boff[b] = A[b];
        __syncthreads();
        for (int o = 1; o < nb2; o <<= 1) {  // Hillis-Steele inclusive scan
            int i1 = tid, i2 = tid + 1024;
            int v1 = 0, v2 = 0;
            if (i1 < nb2 && i1 >= o) v1 = Boff[i1 - o];
            if (i2 < nb2 && i2 >= o) v2 = Boff[i2 - o];
            __syncthreads();
            if (i1 < nb2) Boff[i1] += v1;
            if (i2 < nb2) Boff[i2] += v2;
            __syncthreads();
        }
        for (int b = tid; b < nb2; b += 1024) {
            int cnt = A[b];
            Boff[b] -= cnt;                 // exclusive start
            C[b] = cnt ? atomicAdd(&cursor[b], cnt) : 0;
        }
        __syncthreads();
        for (int b = tid; b < nb2; b += 1024) A[b] = 0;   // ranks
        __syncthreads();
        #pragma unroll
        for (int u = 0; u < 9; u++) {
            int d = cdv[u];
            if (d < 0) continue;
            int f = d >> 6;
            int r = atomicAdd(&A[f], 1);
            buf[Boff[f] + r] = cs[u] | ((d & 63) << 17);
        }
        __syncthreads();
        int total = iend - ibeg;
        if (total > CHMAX) total = CHMAX;
        if (total < 0) total = 0;
        for (int j = tid; j < total; j += 1024) {
            int lo = 0, hi = nb2 - 1;       // last f with Boff[f] <= j
            while (lo < hi) {
                int mid = (lo + hi + 1) >> 1;
                if (Boff[mid] <= j) lo = mid; else hi = mid - 1;
            }
            int f = lo;
            int pos = C[f] + (j - Boff[f]);
            pos = pos < CAPH ? pos : CAPH - 1;
            size_t addr = (size_t)(f >> 1) * CAP + ((f & 1) ? (CAP - 1 - pos) : pos);
            pairs[addr] = buf[j];
        }
    }
}

// ---- Per-half CSR build + layer-1 softmax-aggregate (R25 form: head-per-
// lane 4ch, adaptive-compute 4-volley).
__global__ __launch_bounds__(256) void csragg1_kernel(
        const int* __restrict__ pairs, const int* __restrict__ btotal,
        int NB, int N,
        int* __restrict__ ssorted, int* __restrict__ rs, int* __restrict__ re,
        const float* __restrict__ a_src1, const float* __restrict__ addst,
        const _Float16* __restrict__ hpre1h, const float* __restrict__ b1,
        const float* __restrict__ vs, const float* __restrict__ vd,
        _Float16* __restrict__ hpost1h,
        float* __restrict__ as2n, float* __restrict__ ad2n) {
    __shared__ int deg[64];
    __shared__ int s[64];
    __shared__ int cur[64];
    __shared__ __attribute__((aligned(16))) int lds_sorted[CAPH];
    int tid = threadIdx.x, bh = blockIdx.x;
    int B = bh >> 1, half = bh & 1;
    int nb0 = (B << 7) + (half << 6);
    int cnt_nodes = min(64, N - nb0);      // may be <= 0 for the tail half
    int c = min(btotal[bh], CAPH);         // this half's edge count
    int rbase = B * CAP + (half ? CAP - c : 0);
    if (tid < 64) deg[tid] = 0;
    __syncthreads();
    for (int j = tid; j < c; j += 256)
        atomicAdd(&deg[(pairs[rbase + j] >> 17) & 63], 1);
    __syncthreads();
    if (tid < 64) s[tid] = deg[tid];
    __syncthreads();
    for (int o = 1; o < 64; o <<= 1) {
        int v = 0;
        if (tid < 64 && tid >= o) v = s[tid - o];
        __syncthreads();
        if (tid < 64) s[tid] += v;
        __syncthreads();
    }
    if (tid < 64) {
        int ex = s[tid] - deg[tid];        // half-local exclusive offset
        cur[tid] = ex;
        if (tid < cnt_nodes) {
            rs[nb0 + tid] = bh * CAPH + ex;   // global ssorted offsets for agg2
            re[nb0 + tid] = bh * CAPH + ex + deg[tid];
        }
    }
    __syncthreads();
    for (int j = tid; j < c; j += 256) {   // 2nd region read: L2-hot
        int p = pairs[rbase + j];
        int pos = atomicAdd(&cur[(p >> 17) & 63], 1);
        lds_sorted[pos < CAPH ? pos : CAPH - 1] = p & 0x1FFFF;
    }
    __syncthreads();

    // Coalesced stream-out for agg2 (fire-and-forget; phase B reads only LDS).
    {
        int t4 = c >> 2;
        const int4* ls4 = (const int4*)lds_sorted;
        int4* gs4 = (int4*)(ssorted + (size_t)bh * CAPH);
        for (int j = tid; j < t4; j += 256) gs4[j] = ls4[j];
        for (int j = (t4 << 2) + tid; j < c; j += 256)
            ssorted[(size_t)bh * CAPH + j] = lds_sorted[j];
    }

    // Phase B: wave w handles nodes ln = w*16 + r. head-per-lane,
    // adaptive-compute 4-volley.
    int wave = tid >> 6;
    int lane = tid & 63;
    int head = lane & 3, er = lane >> 2;
    int c0 = head * 4;
    half2v w01, w23;
    w01.x = (_Float16)a_src1[c0];     w01.y = (_Float16)a_src1[c0 + 1];
    w23.x = (_Float16)a_src1[c0 + 2]; w23.y = (_Float16)a_src1[c0 + 3];
    for (int r = 0; r < 16; r++) {
        int ln = (wave << 4) + r;
        if (ln >= cnt_nodes) break;
        int node = nb0 + ln;
        int end = cur[ln];                 // half-local end
        int start = end - deg[ln];
        float adh = addst[node * 4 + head];
        float den = 0.f, a0 = 0.f, a1 = 0.f, a2 = 0.f, a3 = 0.f;
        int last = end - 1;   // deg >= 1 always (self-loop)
        for (int jb = start; jb < end; jb += 64) {
            int m = end - jb;              // wave-uniform remaining count
            int j0 = jb + er, j1 = j0 + 16, j2 = j0 + 32, j3 = j0 + 48;
            int k0 = min(j0, last), k1 = min(j1, last);
            int k2 = min(j2, last), k3 = min(j3, last);
            int s0 = lds_sorted[k0];
            int s1 = lds_sorted[k1];
            int s2 = lds_sorted[k2];
            int s3 = lds_sorted[k3];
            half4v h0 = *(const half4v*)(hpre1h + (size_t)s0 * 16 + c0);
            half4v h1 = *(const half4v*)(hpre1h + (size_t)s1 * 16 + c0);
            half4v h2 = *(const half4v*)(hpre1h + (size_t)s2 * 16 + c0);
            half4v h3 = *(const half4v*)(hpre1h + (size_t)s3 * 16 + c0);
            {   // slot group 0: always
                float p0 = hdot2a(__builtin_shufflevector(h0, h0, 0, 1), w01,
                           hdot2a(__builtin_shufflevector(h0, h0, 2, 3), w23, 0.f));
                float wt0 = (j0 <= last) ? lw(p0 + adh) : 0.f;
                den += wt0;
                a0 += (float)h0.x * wt0; a1 += (float)h0.y * wt0;
                a2 += (float)h0.z * wt0; a3 += (float)h0.w * wt0;
            }
            if (m > 16) {
                float p1 = hdot2a(__builtin_shufflevector(h1, h1, 0, 1), w01,
                           hdot2a(__builtin_shufflevector(h1, h1, 2, 3), w23, 0.f));
                float wt1 = (j1 <= last) ? lw(p1 + adh) : 0.f;
                den += wt1;
                a0 += (float)h1.x * wt1; a1 += (float)h1.y * wt1;
                a2 += (float)h1.z * wt1; a3 += (float)h1.w * wt1;
            }
            if (m > 32) {
                float p2 = hdot2a(__builtin_shufflevector(h2, h2, 0, 1), w01,
                           hdot2a(__builtin_shufflevector(h2, h2, 2, 3), w23, 0.f));
                float wt2 = (j2 <= last) ? lw(p2 + adh) : 0.f;
                den += wt2;
                a0 += (float)h2.x * wt2; a1 += (float)h2.y * wt2;
                a2 += (float)h2.z * wt2; a3 += (float)h2.w * wt2;
            }
            if (m > 48) {
                float p3 = hdot2a(__builtin_shufflevector(h3, h3, 0, 1), w01,
                           hdot2a(__builtin_shufflevector(h3, h3, 2, 3), w23, 0.f));
                float wt3 = (j3 <= last) ? lw(p3 + adh) : 0.f;
                den += wt3;
                a0 += (float)h3.x * wt3; a1 += (float)h3.y * wt3;
                a2 += (float)h3.z * wt3; a3 += (float)h3.w * wt3;
            }
        }
        a0 += __shfl_xor(a0, 4);  a1 += __shfl_xor(a1, 4);  a2 += __shfl_xor(a2, 4);  a3 += __shfl_xor(a3, 4);  den += __shfl_xor(den, 4);
        a0 += __shfl_xor(a0, 8);  a1 += __shfl_xor(a1, 8);  a2 += __shfl_xor(a2, 8);  a3 += __shfl_xor(a3, 8);  den += __shfl_xor(den, 8);
        a0 += __shfl_xor(a0, 16); a1 += __shfl_xor(a1, 16); a2 += __shfl_xor(a2, 16); a3 += __shfl_xor(a3, 16); den += __shfl_xor(den, 16);
        a0 += __shfl_xor(a0, 32); a1 += __shfl_xor(a1, 32); a2 += __shfl_xor(a2, 32); a3 += __shfl_xor(a3, 32); den += __shfl_xor(den, 32);
        if (er == 0) {
            float inv = 1.f / (den + 1e-16f);
            float o0 = mishf(a0 * inv + b1[c0]);
            float o1 = mishf(a1 * inv + b1[c0 + 1]);
            float o2 = mishf(a2 * inv + b1[c0 + 2]);
            float o3 = mishf(a3 * inv + b1[c0 + 3]);
            half4v oh;
            oh.x = (_Float16)o0; oh.y = (_Float16)o1;
            oh.z = (_Float16)o2; oh.w = (_Float16)o3;
            *(half4v*)(hpost1h + (size_t)node * 16 + c0) = oh;
            float ps = o0 * vs[c0] + o1 * vs[c0 + 1] + o2 * vs[c0 + 2] + o3 * vs[c0 + 3];
            float pd = o0 * vd[c0] + o1 * vd[c0 + 1] + o2 * vd[c0 + 2] + o3 * vd[c0 + 3];
            ps += __shfl_xor(ps, 1); pd += __shfl_xor(pd, 1);
            ps += __shfl_xor(ps, 2); pd += __shfl_xor(pd, 2);
            if (head == 0) { as2n[node] = ps; ad2n[node] = pd; }
        }
    }
}

// ---- Layer-2 softmax-aggregate (R25 form: one node per wave, quarter-per-
// lane 4ch, adaptive-compute volley).
__global__ __launch_bounds__(256) void agg2_kernel(
        const int* __restrict__ rs, const int* __restrict__ re,
        const int* __restrict__ ssorted,
        const float* __restrict__ as2n, const float* __restrict__ ad2n,
        const _Float16* __restrict__ hpost1h,
        float* __restrict__ agg16, float* __restrict__ denv, int N) {
    int wave = threadIdx.x >> 6;
    int lane = threadIdx.x & 63;
    int node = blockIdx.x * 4 + wave;
    if (node >= N) return;
    int start = rs[node], end = re[node];
    int q = lane & 3, er = lane >> 2;
    int c0 = q * 4;
    float adh = ad2n[node];
    const _Float16* hb = hpost1h + c0;
    float den = 0.f, a0 = 0.f, a1 = 0.f, a2 = 0.f, a3 = 0.f;
    int last = end - 1;
    for (int jb = start; jb < end; jb += 64) {
        int m = end - jb;                  // wave-uniform remaining count
        int j0 = jb + er, j1 = j0 + 16, j2 = j0 + 32, j3 = j0 + 48;
        int k0 = min(j0, last), k1 = min(j1, last);
        int k2 = min(j2, last), k3 = min(j3, last);
        int s0 = __builtin_nontemporal_load(ssorted + k0);
        int s1 = __builtin_nontemporal_load(ssorted + k1);
        int s2 = __builtin_nontemporal_load(ssorted + k2);
        int s3 = __builtin_nontemporal_load(ssorted + k3);
        float v0 = as2n[s0];
        float v1 = as2n[s1];
        float v2 = as2n[s2];
        float v3 = as2n[s3];
        half4v h0 = *(const half4v*)(hb + (size_t)s0 * 16);
        half4v h1 = *(const half4v*)(hb + (size_t)s1 * 16);
        half4v h2 = *(const half4v*)(hb + (size_t)s2 * 16);
        half4v h3 = *(const half4v*)(hb + (size_t)s3 * 16);
        {   // slot group 0: always
            float wt0 = (j0 <= last) ? lw(v0 + adh) : 0.f;
            den += wt0;
            a0 += (float)h0.x * wt0; a1 += (float)h0.y * wt0;
            a2 += (float)h0.z * wt0; a3 += (float)h0.w * wt0;
        }
        if (m > 16) {
            float wt1 = (j1 <= last) ? lw(v1 + adh) : 0.f;
            den += wt1;
            a0 += (float)h1.x * wt1; a1 += (float)h1.y * wt1;
            a2 += (float)h1.z * wt1; a3 += (float)h1.w * wt1;
        }
        if (m > 32) {
            float wt2 = (j2 <= last) ? lw(v2 + adh) : 0.f;
            den += wt2;
            a0 += (float)h2.x * wt2; a1 += (float)h2.y * wt2;
            a2 += (float)h2.z * wt2; a3 += (float)h2.w * wt2;
        }
        if (m > 48) {
            float wt3 = (j3 <= last) ? lw(v3 + adh) : 0.f;
            den += wt3;
            a0 += (float)h3.x * wt3; a1 += (float)h3.y * wt3;
            a2 += (float)h3.z * wt3; a3 += (float)h3.w * wt3;
        }
    }
    a0 += __shfl_xor(a0, 4);  a1 += __shfl_xor(a1, 4);  a2 += __shfl_xor(a2, 4);  a3 += __shfl_xor(a3, 4);  den += __shfl_xor(den, 4);
    a0 += __shfl_xor(a0, 8);  a1 += __shfl_xor(a1, 8);  a2 += __shfl_xor(a2, 8);  a3 += __shfl_xor(a3, 8);  den += __shfl_xor(den, 8);
    a0 += __shfl_xor(a0, 16); a1 += __shfl_xor(a1, 16); a2 += __shfl_xor(a2, 16); a3 += __shfl_xor(a3, 16); den += __shfl_xor(den, 16);
    a0 += __shfl_xor(a0, 32); a1 += __shfl_xor(a1, 32); a2 += __shfl_xor(a2, 32); a3 += __shfl_xor(a3, 32); den += __shfl_xor(den, 32);
    if (er == 0) {
        float4 o; o.x = a0; o.y = a1; o.z = a2; o.w = a3;
        *(float4*)(agg16 + (size_t)node * 16 + c0) = o;
        if (q == 0) denv[node] = den;
    }
}

// ---- Fused layer-2 GEMM epilogue + mean pool (R25 form: 128 nodes/block).
__global__ void post2pool_kernel(const float* __restrict__ agg16, const float* __restrict__ denv,
                                 const float* __restrict__ W2, const float* __restrict__ b2,
                                 const int* __restrict__ batch,
                                 float* __restrict__ pool, float* __restrict__ cnt, int N) {
    __shared__ float Wl[16 * 32];
    int tid = threadIdx.x;
    for (int i = tid; i < 512; i += 256) Wl[i] = W2[i];
    __syncthreads();
    int r = tid >> 5, ch = tid & 31;
    float bc = b2[ch];
    int base = blockIdx.x * 128;
    int cur = -1;
    float sum = 0.f, c = 0.f;
    for (int it = 0; it < 16; it++) {
        int n = base + it * 8 + r;
        if (n >= N) break;
        int g = batch[n];
        if (g != cur) {
            if (cur >= 0) {
                atomicAdd(&pool[cur * 32 + ch], sum);
                if (ch == 0) atomicAdd(&cnt[cur], c);
            }
            cur = g; sum = 0.f; c = 0.f;
        }
        const float* ar = agg16 + (size_t)n * 16;
        float acc = 0.f;
        #pragma unroll
        for (int k = 0; k < 16; k++) acc += ar[k] * Wl[k * 32 + ch];
        float val = mishf(acc / (denv[n] + 1e-16f) + bc);
        sum += val;
        c += 1.f;
    }
    if (cur >= 0) {
        atomicAdd(&pool[cur * 32 + ch], sum);
        if (ch == 0) atomicAdd(&cnt[cur], c);
    }
}

__global__ void fin_kernel(const float* __restrict__ pool, const float* __restrict__ cnt,
                           float* __restrict__ out, int NG) {
    int i = blockIdx.x * blockDim.x + threadIdx.x;
    if (i >= NG * 32) return;
    out[i] = pool[i] / fmaxf(cnt[i >> 5], 1.0f);
}

extern "C" void kernel_launch(void* const* d_in, const int* in_sizes, int n_in,
                              void* d_out, int out_size, void* d_ws, size_t ws_size,
                              hipStream_t stream) {
    const float* x   = (const float*)d_in[0];
    const int* eidx  = (const int*)d_in[1];
    const int* batch = (const int*)d_in[2];
    const float* W1  = (const float*)d_in[3];
    const float* b1  = (const float*)d_in[4];
    const float* as1 = (const float*)d_in[5];
    const float* ad1 = (const float*)d_in[6];
    const float* W2  = (const float*)d_in[7];
    const float* b2  = (const float*)d_in[8];
    const float* as2 = (const float*)d_in[9];
    const float* ad2 = (const float*)d_in[10];
    float* out = (float*)d_out;

    int N = in_sizes[0] / 128;
    int E = in_sizes[1] / 2;
    int Etot = E + N;
    int NG = out_size / 32;
    const int* esrc = eidx;
    const int* edst = eidx + E;

    int NB = (N + 127) >> 7;                 // 128-node slabs (binning grain)
    int NBH = NB * 2;                        // 64-node halves (aggregate grain)
    int NT = (N + 63) >> 6;                  // 64-node gemm tiles
    int CH = (Etot + SB - 1) / SB;           // edges per binning block

    char* p = (char*)d_ws;
    auto alloc = [&](size_t nbytes) {
        p = (char*)(((uintptr_t)p + 15) & ~(uintptr_t)15);
        void* r = (void*)p; p += nbytes; return r;
    };
    int* pairs        = (int*)alloc((size_t)NB * CAP * 4);
    int* ssorted      = (int*)alloc((size_t)NBH * CAPH * 4);
    int* rs           = (int*)alloc((size_t)N * 4);
    int* re           = (int*)alloc((size_t)N * 4);
    _Float16* hpre1h  = (_Float16*)alloc((size_t)N * 16 * 2);
    _Float16* hpost1h = (_Float16*)alloc((size_t)N * 16 * 2);
    float* addst1  = (float*)alloc((size_t)N * 4 * 4);
    float* as2n    = (float*)alloc((size_t)N * 4);
    float* ad2n    = (float*)alloc((size_t)N * 4);
    float* agg16   = (float*)alloc((size_t)N * 16 * 4);
    float* denv    = (float*)alloc((size_t)N * 4);
    float* vs      = (float*)alloc(16 * 4);
    float* vd      = (float*)alloc(16 * 4);
    // ---- zero-init region: cursor + pool + cnt contiguous -> ONE memset
    char* zbase    = (char*)(((uintptr_t)p + 15) & ~(uintptr_t)15);
    int* cursor    = (int*)alloc((size_t)NBH * 4);
    float* pool    = (float*)alloc((size_t)NG * 32 * 4);
    float* cnt     = (float*)alloc((size_t)NG * 4);
    size_t zbytes  = (size_t)(p - zbase);

    hipMemsetAsync(zbase, 0, zbytes, stream);

    front_kernel<<<GB + SB, 1024, 0, stream>>>(x, W1, ad1, W2, as2, ad2,
                                               hpre1h, addst1, vs, vd,
                                               esrc, edst, E, Etot, CH, NB, N, NT,
                                               cursor, pairs);
    csragg1_kernel<<<NBH, 256, 0, stream>>>(pairs, cursor, NB, N,
                                            ssorted, rs, re, as1, addst1, hpre1h,
                                            b1, vs, vd, hpost1h, as2n, ad2n);
    agg2_kernel<<<(N + 3) / 4, 256, 0, stream>>>(rs, re, ssorted, as2n, ad2n, hpost1h,
                                                 agg16, denv, N);
    post2pool_kernel<<<(N + 127) / 128, 256, 0, stream>>>(agg16, denv, W2, b2, batch,
                                                          pool, cnt, N);
    fin_kernel<<<(NG * 32 + 255) / 256, 256, 0, stream>>>(pool, cnt, out, NG);
}